// Round 2
// baseline (104.849 us; speedup 1.0000x reference)
//
#include <hip/hip_runtime.h>

// n-step return: T=1024, B=4096, gamma=0.99, horizon=16, fp32 in/out.
// G[t,b] = sum_{h=0}^{15} g^h * rm[t+h,b]  (rm = rewards*masks, zero-padded past T)
//        + g^{min(t+16,T)-t} * values[min(t+15,T-1), b]
//
// R4: float4 + CT=4 (was CT=8). R3 post-mortem: float4/CT=8 regressed vs
// scalar (95.9 vs 89.8 end-to-end) because 124 payload VGPRs under
// launch_bounds(256,2) capped residency at 8 waves/CU — traded away the TLP
// that hides VMEM latency (kernel is latency-bound: compulsory HBM traffic is
// only 64 MB ~ 10us; harness fills prove 6.3 TB/s reachable; halo re-reads
// are L2/L3-resident). CT=4 cuts payload to 92 VGPRs -> <=128 band ->
// 4 waves/SIMD = 16 waves/CU (2x R3), 42 loads/thread still fully staged.
// Halo amp 19/4 = 4.75x on r,m = ~152 MB L2 traffic (~4us @ 34.5 TB/s) — cheap.

constexpr int   T_DIM  = 1024;
constexpr int   B_DIM  = 4096;
constexpr int   B4     = B_DIM / 4;   // 1024 float4 columns
constexpr int   H      = 16;          // horizon
constexpr int   CT     = 4;           // timesteps per thread
constexpr int   HALO   = H - 1;       // 15
constexpr int   ROWS   = CT + HALO;   // 19 staged rm rows
constexpr float GAMMA  = 0.99f;

constexpr float gpow_c(int n) {
    float g = 1.0f;
    for (int i = 0; i < n; ++i) g *= GAMMA;
    return g;
}
constexpr float G16 = gpow_c(16);

__device__ __forceinline__ float4 f4_mul(float4 a, float4 b) {
    return make_float4(a.x * b.x, a.y * b.y, a.z * b.z, a.w * b.w);
}
// s*a + b, componentwise
__device__ __forceinline__ float4 f4_fma(float s, float4 a, float4 b) {
    return make_float4(fmaf(s, a.x, b.x), fmaf(s, a.y, b.y),
                       fmaf(s, a.z, b.z), fmaf(s, a.w, b.w));
}

__global__ __launch_bounds__(256, 4)
void NStepReturn_88691074662796_kernel(const float4* __restrict__ rewards,
                                       const float4* __restrict__ values,
                                       const float4* __restrict__ masks,
                                       float4* __restrict__ out)
{
    const int b4 = blockIdx.x * 256 + threadIdx.x;        // float4 column
    const int t0 = blockIdx.y * CT;                       // chunk start

    // ---- stage rm = rewards*masks for all needed rows (max loads in flight) ----
    float4 rm[ROWS];
    #pragma unroll
    for (int i = 0; i < ROWS; ++i) {
        const int t = t0 + i;                             // may exceed T-1 in last chunks
        if (t < T_DIM) {
            const float4 r = rewards[t * B4 + b4];
            const float4 m = masks[t * B4 + b4];
            rm[i] = f4_mul(r, m);
        } else {
            rm[i] = make_float4(0.0f, 0.0f, 0.0f, 0.0f);
        }
    }
    float4 v[CT];
    #pragma unroll
    for (int i = 0; i < CT; ++i) {
        const int vi = min(t0 + i + H - 1, T_DIM - 1);
        v[i] = values[vi * B4 + b4];
    }

    // ---- init: W(t_last) = sum_{h=0}^{15} g^h rm[t_last+h] (Horner) ----
    float4 W = make_float4(0.0f, 0.0f, 0.0f, 0.0f);
    #pragma unroll
    for (int h = H - 1; h >= 0; --h) W = f4_fma(GAMMA, W, rm[CT - 1 + h]);

    {   // bootstrap for t_last
        const int t = t0 + CT - 1;
        float gb = G16;
        if (t + H > T_DIM) {                              // uniform; last chunks only
            gb = 1.0f;
            for (int k = 0; k < T_DIM - t; ++k) gb *= GAMMA;
        }
        out[t * B4 + b4] = f4_fma(gb, v[CT - 1], W);
    }

    // ---- backward sweep: W(t) = rm[t] + g*W(t+1) - g^16*rm[t+16] ----
    #pragma unroll
    for (int j = CT - 2; j >= 0; --j) {
        const int t = t0 + j;
        W = f4_fma(GAMMA, W, rm[j]);                      // rm[t] + g*W
        W = f4_fma(-G16, rm[j + H], W);                   // - g^16 * rm[t+16]

        float gb = G16;
        if (t + H > T_DIM) {                              // uniform; last chunks only
            gb = 1.0f;
            for (int k = 0; k < T_DIM - t; ++k) gb *= GAMMA;
        }
        out[t * B4 + b4] = f4_fma(gb, v[j], W);
    }
}

extern "C" void kernel_launch(void* const* d_in, const int* in_sizes, int n_in,
                              void* d_out, int out_size, void* d_ws, size_t ws_size,
                              hipStream_t stream) {
    const float4* rewards = (const float4*)d_in[0];
    const float4* values  = (const float4*)d_in[1];
    const float4* masks   = (const float4*)d_in[2];
    float4* out = (float4*)d_out;

    dim3 grid(B4 / 256, T_DIM / CT);   // (4, 256) = 1024 blocks, 4 waves each
    dim3 block(256);
    NStepReturn_88691074662796_kernel<<<grid, block, 0, stream>>>(rewards, values, masks, out);
}

// Round 3
// 89.622 us; speedup vs baseline: 1.1699x; 1.1699x over previous
//
#include <hip/hip_runtime.h>

// n-step return: T=1024, B=4096, gamma=0.99, horizon=16, fp32 in/out.
// G[t,b] = sum_{h=0}^{15} g^h * rm[t+h,b]  (rm = rewards*masks, zero-padded past T)
//        + g^{min(t+16,T)-t} * values[min(t+15,T-1), b]
//
// R5: scalar loads, CT=32. Evidence across R2/R3/R4: dur_us is monotone in
// TOTAL traffic (94/124/184 MB -> 89.8/95.9/104.8), while doubling waves/CU
// (R4 vs R3) did nothing. => traffic-bound via halo amplification (CT+15)/CT,
// not VMEM-issue-bound. So: keep the R2 champion's scalar structure (4B/lane,
// max thread count) and just double CT: 16 -> 32.
//   traffic: (47/32)*32MB + 16MB v + 16MB write = 79 MB  (champion was 94)
//   waves:   4096 cols x 32 chunks = 2048 waves = 8/CU = 2/SIMD (sufficient
//            per R3-vs-R4: TLP above this showed no effect)
//   VGPRs:   peak staging r[47]+m[47]+v[32] = 126 payload; launch_bounds(256,2)
//            caps at 256 so all loads stage fully (max MLP), no spill.

constexpr int   T_DIM  = 1024;
constexpr int   B_DIM  = 4096;
constexpr int   H      = 16;          // horizon
constexpr int   CT     = 32;          // timesteps per thread
constexpr int   HALO   = H - 1;       // 15
constexpr int   ROWS   = CT + HALO;   // 47 staged rm rows
constexpr float GAMMA  = 0.99f;

constexpr float gpow_c(int n) {
    float g = 1.0f;
    for (int i = 0; i < n; ++i) g *= GAMMA;
    return g;
}
constexpr float G16 = gpow_c(16);

__global__ __launch_bounds__(256, 2)
void NStepReturn_88691074662796_kernel(const float* __restrict__ rewards,
                                       const float* __restrict__ values,
                                       const float* __restrict__ masks,
                                       float* __restrict__ out)
{
    const int b  = blockIdx.x * 256 + threadIdx.x;        // column
    const int t0 = blockIdx.y * CT;                       // chunk start

    // ---- stage ALL global loads as independent ops (max loads-in-flight) ----
    float r[ROWS], m[ROWS], v[CT];
    #pragma unroll
    for (int i = 0; i < ROWS; ++i) {
        const int t = t0 + i;                             // may exceed T-1 in last chunk
        if (t < T_DIM) {
            r[i] = rewards[t * B_DIM + b];
            m[i] = masks[t * B_DIM + b];
        } else {
            r[i] = 0.0f;
            m[i] = 0.0f;
        }
    }
    #pragma unroll
    for (int i = 0; i < CT; ++i) {
        const int vi = min(t0 + i + H - 1, T_DIM - 1);
        v[i] = values[vi * B_DIM + b];
    }

    // ---- rm products (reuse r[]) ----
    #pragma unroll
    for (int i = 0; i < ROWS; ++i) r[i] *= m[i];

    // ---- init: W(t_last) = sum_{h=0}^{15} g^h rm[t_last+h] (Horner) ----
    float W = 0.0f;
    #pragma unroll
    for (int h = H - 1; h >= 0; --h) W = fmaf(GAMMA, W, r[CT - 1 + h]);

    {   // bootstrap for t_last
        const int t = t0 + CT - 1;
        float gb = G16;
        if (t + H > T_DIM) {                              // uniform; last chunk only
            gb = 1.0f;
            for (int k = 0; k < T_DIM - t; ++k) gb *= GAMMA;
        }
        out[t * B_DIM + b] = fmaf(gb, v[CT - 1], W);
    }

    // ---- backward sweep: W(t) = rm[t] + g*W(t+1) - g^16*rm[t+16] ----
    #pragma unroll
    for (int j = CT - 2; j >= 0; --j) {
        const int t = t0 + j;
        W = fmaf(GAMMA, W, r[j]);                         // rm[t] + g*W
        W = fmaf(-G16, r[j + H], W);                      // - g^16 * rm[t+16]

        float gb = G16;
        if (t + H > T_DIM) {                              // uniform; last chunk only
            gb = 1.0f;
            for (int k = 0; k < T_DIM - t; ++k) gb *= GAMMA;
        }
        out[t * B_DIM + b] = fmaf(gb, v[j], W);
    }
}

extern "C" void kernel_launch(void* const* d_in, const int* in_sizes, int n_in,
                              void* d_out, int out_size, void* d_ws, size_t ws_size,
                              hipStream_t stream) {
    const float* rewards = (const float*)d_in[0];
    const float* values  = (const float*)d_in[1];
    const float* masks   = (const float*)d_in[2];
    float* out = (float*)d_out;

    dim3 grid(B_DIM / 256, T_DIM / CT);   // (16, 32) = 512 blocks
    dim3 block(256);
    NStepReturn_88691074662796_kernel<<<grid, block, 0, stream>>>(rewards, values, masks, out);
}